// Round 16
// baseline (488.362 us; speedup 1.0000x reference)
//
#include <hip/hip_runtime.h>

#define DEV __device__ __forceinline__

typedef short  bf16x8 __attribute__((ext_vector_type(8)));
typedef float  f32x4  __attribute__((ext_vector_type(4)));

DEV unsigned short f2b(float f) {
    unsigned int u = __float_as_uint(f);
    u += 0x7fffu + ((u >> 16) & 1u);
    return (unsigned short)(u >> 16);
}
DEV float b2f(unsigned short h) { return __uint_as_float((unsigned int)h << 16); }
DEV float silu(float x) { return x / (1.f + __expf(-x)); }
DEV float fexp2(float x) { return __builtin_amdgcn_exp2f(x); }   // raw v_exp_f32
DEV float flog2(float x) { return __builtin_amdgcn_logf(x); }    // raw v_log_f32

// async global->LDS, 16B per lane: HW writes lane l at ldsbase + l*16
typedef const __attribute__((address_space(1))) unsigned int GU32;
typedef __attribute__((address_space(3))) unsigned int LU32;
DEV void gload16(const unsigned short* g, unsigned short* l) {
    __builtin_amdgcn_global_load_lds((GU32*)g, (LU32*)l, 16, 0, 0);
}

// ---------------------------------------------------------------------------
// f32 -> bf16 elementwise convert (n multiple of 4)
__global__ __launch_bounds__(256) void k_cvt(const float* __restrict__ s,
                                             unsigned short* __restrict__ d, int n) {
    int i = (blockIdx.x * 256 + threadIdx.x) * 4;
    if (i + 3 < n) {
        float4 v = *(const float4*)(s + i);
        ushort4 o;
        o.x = f2b(v.x); o.y = f2b(v.y); o.z = f2b(v.z); o.w = f2b(v.w);
        *(ushort4*)(d + i) = o;
    }
}

// up_w (512 x 512 x 4) [i,o,k] -> upT[(k*512+o)*512 + i] bf16
__global__ void k_upT(const float* __restrict__ up_w, unsigned short* __restrict__ upT) {
    __shared__ float t[32][33];
    int tx = threadIdx.x, ty = threadIdx.y;
    int o0 = blockIdx.x * 32, i0 = blockIdx.y * 32, kz = blockIdx.z;
    t[ty][tx] = up_w[(size_t)(i0 + ty) * 2048 + (o0 + tx) * 4 + kz];
    __syncthreads();
    upT[(size_t)(kz * 512 + o0 + ty) * 512 + i0 + tx] = f2b(t[tx][ty]);
}

// dt packing: split-bf16 exact GEMM operands (K=32 -> K=128).
// A: dtraw = xdbl[:, 0:32] -> Ap[m][0:32]=xh, [32:64]=xl, [64:96]=xh, [96:128]=xl
__global__ __launch_bounds__(256) void k_dtpackA(const float* __restrict__ xdbl,
                                                 unsigned short* __restrict__ Ap) {
    int i = blockIdx.x * 256 + threadIdx.x;   // (m, r), r fastest
    int m = i >> 5, r = i & 31;
    float x = xdbl[(size_t)m * 64 + r];
    unsigned short xh = f2b(x);
    unsigned short xl = f2b(x - b2f(xh));
    size_t base = (size_t)m * 128;
    Ap[base + r]      = xh;
    Ap[base + 32 + r] = xl;
    Ap[base + 64 + r] = xh;
    Ap[base + 96 + r] = xl;
}

// B: dt_proj_w (1024 x 32) -> Bp[d][0:32]=wh, [32:64]=wl, [64:96]=wl, [96:128]=wh
// sum over K=128: xh*wh + xl*wl + xh*wl + xl*wh = (xh+xl)*(wh+wl)  (exact split)
__global__ __launch_bounds__(256) void k_dtpackB(const float* __restrict__ w,
                                                 unsigned short* __restrict__ Bp) {
    int i = blockIdx.x * 256 + threadIdx.x;   // (d, r)
    int d = i >> 5, r = i & 31;
    float x = w[(size_t)d * 32 + r];
    unsigned short wh = f2b(x);
    unsigned short wl = f2b(x - b2f(wh));
    size_t base = (size_t)d * 128;
    Bp[base + r]      = wh;
    Bp[base + 32 + r] = wl;
    Bp[base + 64 + r] = wl;
    Bp[base + 96 + r] = wh;
}

// ---------------------------------------------------------------------------
// bf16 MFMA GEMM, NT: C[m,n] = sum_k A[m,k]*B[n,k].  BM=128, BK=32, 4 waves,
// m97-style global_load_lds staging (linear LDS, 16B/lane).
// XCD-aware block swizzle (T1): contiguous tile chunks per XCD for L2 reuse.
// OUTMODE 0: f32 out, 1: bf16 out, 2: softplus -> f32 out (hw exp2/log2).
template <int BN, int OUTMODE>
__global__ __launch_bounds__(256) void k_gemm(const unsigned short* __restrict__ A,
                                              const unsigned short* __restrict__ B,
                                              float* __restrict__ Cf,
                                              unsigned short* __restrict__ Cb,
                                              const float* __restrict__ bias,
                                              int M, int N, int K) {
    constexpr int BM = 128, BK = 32;
    constexpr int WM = (BN == 128) ? 64 : 32;
    constexpr int WN = 64;
    constexpr int MI = WM / 16, NI = WN / 16;
    __shared__ unsigned short As[BM * BK];
    __shared__ unsigned short Bs[BN * BK];
    const int tid = threadIdx.x;
    const int wid = tid >> 6, lane = tid & 63;

    // XCD swizzle: hw bids round-robin XCDs; map same-XCD bids to contiguous tiles
    int bid = blockIdx.y * gridDim.x + blockIdx.x;
    const int nwg = gridDim.x * gridDim.y;
    if ((nwg & 7) == 0) {
        int cpx = nwg >> 3;
        bid = (bid & 7) * cpx + (bid >> 3);
    }
    const int bx = bid % gridDim.x, by = bid / gridDim.x;
    const int m0 = by * BM, n0 = bx * BN;

    int wr, wc;
    if (BN == 128) { wr = wid >> 1; wc = wid & 1; } else { wr = wid; wc = 0; }
    const int wm0 = wr * WM, wn0 = wc * WN;
    const int fr = lane & 15, fh = lane >> 4;

    // staging geometry: wave w stages 16-row strips; lane l -> row w*16+(l>>2),
    // col (l&3)*8 ushorts; LDS dest is wave-uniform strip base (linear layout).
    const int srow = wid * 16 + (lane >> 2);
    const int scol = (lane & 3) * 8;
    const unsigned short* Ag = A + (size_t)(m0 + srow) * K + scol;
    const unsigned short* Bg = B + (size_t)(n0 + srow) * K + scol;
    unsigned short* AsB = &As[wid * 16 * BK];
    unsigned short* BsB = &Bs[wid * 16 * BK];

    f32x4 acc[MI][NI];
#pragma unroll
    for (int i = 0; i < MI; ++i)
#pragma unroll
        for (int j = 0; j < NI; ++j) acc[i][j] = (f32x4){0.f, 0.f, 0.f, 0.f};

    for (int k0 = 0; k0 < K; k0 += BK) {
        gload16(Ag + k0, AsB);
        gload16(Ag + (size_t)64 * K + k0, AsB + 64 * BK);
        gload16(Bg + k0, BsB);
        if (BN == 128) gload16(Bg + (size_t)64 * K + k0, BsB + 64 * BK);
        __syncthreads();
        bf16x8 av[MI], bv[NI];
#pragma unroll
        for (int mi = 0; mi < MI; ++mi)
            av[mi] = *(const bf16x8*)(&As[(wm0 + mi * 16 + fr) * BK + fh * 8]);
#pragma unroll
        for (int ni = 0; ni < NI; ++ni)
            bv[ni] = *(const bf16x8*)(&Bs[(wn0 + ni * 16 + fr) * BK + fh * 8]);
#pragma unroll
        for (int mi = 0; mi < MI; ++mi)
#pragma unroll
            for (int ni = 0; ni < NI; ++ni)
                acc[mi][ni] = __builtin_amdgcn_mfma_f32_16x16x32_bf16(av[mi], bv[ni],
                                                                      acc[mi][ni], 0, 0, 0);
        __syncthreads();
    }
    constexpr float LOG2E = 1.4426950408889634f;
    constexpr float LN2   = 0.6931471805599453f;
#pragma unroll
    for (int mi = 0; mi < MI; ++mi) {
#pragma unroll
        for (int ni = 0; ni < NI; ++ni) {
            int col = n0 + wn0 + ni * 16 + fr;
            float bb = bias ? bias[col] : 0.f;
#pragma unroll
            for (int j = 0; j < 4; ++j) {
                int row = m0 + wm0 + mi * 16 + fh * 4 + j;
                float v = acc[mi][ni][j] + bb;
                if (OUTMODE == 0)      Cf[(size_t)row * N + col] = v;
                else if (OUTMODE == 1) Cb[(size_t)row * N + col] = f2b(v);
                else                   Cf[(size_t)row * N + col] =
                    (v > 20.f) ? v : flog2(1.f + fexp2(v * LOG2E)) * LN2;
            }
        }
    }
}

// ---------------------------------------------------------------------------
// assemble cat row-major (8192 x 1024) bf16: [0,512)=xu from P, [512,1024)=skip
__global__ __launch_bounds__(256) void k_assemble(const float* __restrict__ P,
                                                  const float* __restrict__ skip,
                                                  const float* __restrict__ up_b,
                                                  unsigned short* __restrict__ catbf) {
    int bx = blockIdx.x;
    int m = bx >> 2;
    int c = (bx & 3) * 256 + threadIdx.x;
    int b = m >> 10, t = m & 1023, j = t >> 1;
    float v;
    if (c < 512) {
        size_t rb = (size_t)((b << 9) + j) * 2048;
        if (t & 1) {                       // odd t: k=2 @ j, k=0 @ j+1
            v = P[rb + 1024 + c];
            if (j + 1 < 512) v += P[rb + 2048 + c];
        } else {                           // even t: k=3 @ j-1, k=1 @ j
            v = P[rb + 512 + c];
            if (j >= 1) v += P[rb - 2048 + 1536 + c];
        }
        v += up_b[c];
    } else {
        v = skip[(size_t)m * 512 + (c - 512)];
    }
    catbf[(size_t)m * 1024 + c] = f2b(v);
}

// LayerNorm over 512, 4 rows per 256-block, writes bf16
__global__ __launch_bounds__(256) void k_ln(const float* __restrict__ merged,
                                            const float* __restrict__ w,
                                            const float* __restrict__ bvec,
                                            unsigned short* __restrict__ outb) {
    int row = blockIdx.x * 4 + (threadIdx.x >> 6);
    int lane = threadIdx.x & 63;
    const float* r = merged + (size_t)row * 512 + lane * 8;
    float4 v1 = *(const float4*)r;
    float4 v2 = *(const float4*)(r + 4);
    float xv[8] = {v1.x, v1.y, v1.z, v1.w, v2.x, v2.y, v2.z, v2.w};
    float s = 0.f, ss = 0.f;
#pragma unroll
    for (int e = 0; e < 8; ++e) { s += xv[e]; ss += xv[e] * xv[e]; }
#pragma unroll
    for (int m = 1; m < 64; m <<= 1) { s += __shfl_xor(s, m, 64); ss += __shfl_xor(ss, m, 64); }
    float mean = s * (1.f / 512.f);
    float var = ss * (1.f / 512.f) - mean * mean;
    float inv = rsqrtf(var + 1e-5f);
    unsigned short o8[8];
#pragma unroll
    for (int e = 0; e < 8; ++e) {
        int c = lane * 8 + e;
        o8[e] = f2b((xv[e] - mean) * inv * w[c] + bvec[c]);
    }
    *(int4*)(outb + (size_t)row * 512 + lane * 8) = *(const int4*)o8;
}

// causal depthwise conv K=4 + bias + silu; 4 channels/thread, bf16 in/out
__global__ __launch_bounds__(256) void k_conv(const unsigned short* __restrict__ xzb,
                                              const float* __restrict__ cw,
                                              const float* __restrict__ cb,
                                              unsigned short* __restrict__ xcb) {
    int i = blockIdx.x * 256 + threadIdx.x;   // 2.1M threads
    int m = i >> 8;
    int c0 = (i & 255) * 4;
    int l = m & 1023;
    float4 w0 = *(const float4*)(cw + (size_t)(c0 + 0) * 4);
    float4 w1 = *(const float4*)(cw + (size_t)(c0 + 1) * 4);
    float4 w2 = *(const float4*)(cw + (size_t)(c0 + 2) * 4);
    float4 w3 = *(const float4*)(cw + (size_t)(c0 + 3) * 4);
    float4 acc = *(const float4*)(cb + c0);
    const float* wp0 = (const float*)&w0;
    const float* wp1 = (const float*)&w1;
    const float* wp2 = (const float*)&w2;
    const float* wp3 = (const float*)&w3;
#pragma unroll
    for (int k = 0; k < 4; ++k) {
        int lp = l - 3 + k;
        if (lp >= 0) {
            ushort4 xv = *(const ushort4*)(xzb + (size_t)(m - l + lp) * 2048 + c0);
            acc.x = fmaf(wp0[k], b2f(xv.x), acc.x);
            acc.y = fmaf(wp1[k], b2f(xv.y), acc.y);
            acc.z = fmaf(wp2[k], b2f(xv.z), acc.z);
            acc.w = fmaf(wp3[k], b2f(xv.w), acc.w);
        }
    }
    ushort4 o = { f2b(silu(acc.x)), f2b(silu(acc.y)), f2b(silu(acc.z)), f2b(silu(acc.w)) };
    *(ushort4*)(xcb + (size_t)m * 1024 + c0) = o;
}

// ---------------------------------------------------------------------------
// Chunked selective scan, s-split for occupancy.  L=1024, NC=32 chunks of 32.
// Lane pair (2i, 2i+1) covers one d: even lane s in [0,8), odd lane s in [8,16).
// Grid (8 dgrp, 8 b, NC) = 2048 blocks -> 8 blocks/CU (2x TLP vs 16-state map).
// PHASE 0: from h=0, store (exp2(A2*dtsum), h_final) per chunk -> ap, hf.
// PHASE 1: read h_init, compute y (p reduced via shfl_xor(1)), D*u + silu(z).
// Power fast path: A[s]=(s+1)*A[0] -> powers of a1 (guarded, exact fallback).
constexpr int SCAN_NC = 32;
constexpr int SCAN_CL = 32;

template <int PHASE>
__global__ __launch_bounds__(256) void k_scan_chunk(
        const float* __restrict__ dt, const unsigned short* __restrict__ xcb,
        const float* __restrict__ xdbl, const unsigned short* __restrict__ xzb,
        const float* __restrict__ Alog, const float* __restrict__ Dp,
        float* __restrict__ ap, float* __restrict__ hf,
        unsigned short* __restrict__ ybf) {
    constexpr int CL = SCAN_CL;
    const int tid = threadIdx.x;
    const int dl = tid >> 1, sh = tid & 1;         // d-local, s-half
    const int d = blockIdx.x * 128 + dl;
    const int b = blockIdx.y, c = blockIdx.z;
    const size_t mbase = (size_t)b * 1024 + (size_t)c * CL;

    // stage this chunk's B/C slice of xdbl into LDS: [l][0..15]=B, [16..31]=C
    __shared__ float sBC[CL][32];
    {
        int row = tid >> 3, q = tid & 7;   // CL*8 == 256
        *(float4*)&sBC[row][q * 4] =
            *(const float4*)(xdbl + (mbase + row) * 64 + 32 + q * 4);
    }
    __syncthreads();

    constexpr float LOG2E = 1.4426950408889634f;
    float A2[8], h[8];
#pragma unroll
    for (int j = 0; j < 8; ++j) A2[j] = -expf(Alog[d * 16 + sh * 8 + j]) * LOG2E;

    // base (s=0) coefficient lives on the even lane of the pair
    const int lane = tid & 63;
    const float A2b = __shfl(A2[0], lane & 62, 64);

    // integer-ratio check for this half: A2[j] == (sh*8+j+1)*A2b to ~1e-5 rel
    bool powok = true;
#pragma unroll
    for (int j = 0; j < 8; ++j)
        powok = powok && (fabsf(A2[j] - (float)(sh * 8 + j + 1) * A2b) <=
                          1e-5f * fabsf(A2[j]));

    const size_t sumbase = ((size_t)(b * SCAN_NC + c) << 14) + (size_t)d * 16 + sh * 8;
    if (PHASE == 0) {
#pragma unroll
        for (int j = 0; j < 8; ++j) h[j] = 0.f;
    } else {
        *(f32x4*)&h[0] = *(const f32x4*)(hf + sumbase);
        *(f32x4*)&h[4] = *(const f32x4*)(hf + sumbase + 4);
    }
    float dtsum = 0.f;
    const float Dv = (PHASE == 1) ? Dp[d] : 0.f;

    // software-pipelined dt/u loads: issue next-l loads before current compute
    const size_t mrow = mbase * 1024 + d;
    float dtv = dt[mrow];
    float uv  = b2f(xcb[mrow]);
#pragma unroll 2
    for (int l = 0; l < CL; ++l) {
        const size_t m = mbase + l;
        const float dtv_c = dtv, uv_c = uv;
        if (l + 1 < CL) {
            dtv = dt[mrow + (size_t)(l + 1) * 1024];
            uv  = b2f(xcb[mrow + (size_t)(l + 1) * 1024]);
        }
        float zv;
        if (PHASE == 1) zv = b2f(xzb[m * 2048 + 1024 + d]);
        const float dtu = dtv_c * uv_c;
        if (PHASE == 0) dtsum += dtv_c;
        float Bv[8], Cv[8];
        *(float4*)&Bv[0] = *(const float4*)&sBC[l][sh * 8];
        *(float4*)&Bv[4] = *(const float4*)&sBC[l][sh * 8 + 4];
        if (PHASE == 1) {
            *(float4*)&Cv[0] = *(const float4*)&sBC[l][16 + sh * 8];
            *(float4*)&Cv[4] = *(const float4*)&sBC[l][16 + sh * 8 + 4];
        }
        float p = 0.f;
        if (powok) {
            const float a1 = fexp2(dtv_c * A2b);
            float a;
            if (sh == 0) a = a1;
            else { float a2 = a1 * a1, a4 = a2 * a2, a8 = a4 * a4; a = a8 * a1; }
#pragma unroll
            for (int j = 0; j < 8; ++j) {
                h[j] = fmaf(a, h[j], dtu * Bv[j]);
                if (PHASE == 1) p = fmaf(h[j], Cv[j], p);
                a *= a1;
            }
        } else {
#pragma unroll
            for (int j = 0; j < 8; ++j) {
                float a = fexp2(dtv_c * A2[j]);
                h[j] = fmaf(a, h[j], dtu * Bv[j]);
                if (PHASE == 1) p = fmaf(h[j], Cv[j], p);
            }
        }
        if (PHASE == 1) {
            p += __shfl_xor(p, 1, 64);
            if (sh == 0)
                ybf[m * 1024 + d] = f2b((p + Dv * uv_c) * silu(zv));
        }
    }
    if (PHASE == 0) {
        float aprod[8];
        if (powok) {
            const float a1p = fexp2(A2b * dtsum);
            float a;
            if (sh == 0) a = a1p;
            else { float a2 = a1p * a1p, a4 = a2 * a2, a8 = a4 * a4; a = a8 * a1p; }
#pragma unroll
            for (int j = 0; j < 8; ++j) { aprod[j] = a; a *= a1p; }
        } else {
#pragma unroll
            for (int j = 0; j < 8; ++j) aprod[j] = fexp2(A2[j] * dtsum);
        }
        *(f32x4*)(ap + sumbase)     = *(const f32x4*)&aprod[0];
        *(f32x4*)(ap + sumbase + 4) = *(const f32x4*)&aprod[4];
        *(f32x4*)(hf + sumbase)     = *(const f32x4*)&h[0];
        *(f32x4*)(hf + sumbase + 4) = *(const f32x4*)&h[4];
    }
}

// carry scan over chunk summaries; rewrites hf[c] with h_init for chunk c.
__global__ __launch_bounds__(256) void k_scan_carry(const float* __restrict__ ap,
                                                    float* __restrict__ hf) {
    int i = blockIdx.x * 256 + threadIdx.x;   // (b, d*16+s)
    int b = i >> 14, ds = i & 16383;
    float h = 0.f;
    for (int c = 0; c < SCAN_NC; ++c) {
        size_t idx = ((size_t)(b * SCAN_NC + c) << 14) + ds;
        float a = ap[idx], f = hf[idx];
        hf[idx] = h;
        h = fmaf(a, h, f);
    }
}

// ---------------------------------------------------------------------------
extern "C" void kernel_launch(void* const* d_in, const int* in_sizes, int n_in,
                              void* d_out, int out_size, void* d_ws, size_t ws_size,
                              hipStream_t stream) {
    const float* x         = (const float*)d_in[0];
    const float* skip      = (const float*)d_in[1];
    const float* up_w      = (const float*)d_in[2];
    const float* up_b      = (const float*)d_in[3];
    const float* merge_w   = (const float*)d_in[4];
    const float* merge_b   = (const float*)d_in[5];
    const float* ln_w      = (const float*)d_in[6];
    const float* ln_b      = (const float*)d_in[7];
    const float* in_proj_w = (const float*)d_in[8];
    const float* conv_w    = (const float*)d_in[9];
    const float* conv_b    = (const float*)d_in[10];
    const float* x_proj_w  = (const float*)d_in[11];
    const float* dt_proj_w = (const float*)d_in[12];
    const float* dt_proj_b = (const float*)d_in[13];
    const float* A_log     = (const float*)d_in[14];
    const float* D_param   = (const float*)d_in[15];
    const float* out_proj_w= (const float*)d_in[16];
    float* out = (float*)d_out;

    char* ws = (char*)d_ws;
    size_t off = 0;
    auto alloc = [&](size_t bytes) { size_t r = off; off += (bytes + 255) & ~(size_t)255; return r; };

    // persistent
    unsigned short* upT  = (unsigned short*)(ws + alloc(2048ull * 512 * 2));
    unsigned short* mw   = (unsigned short*)(ws + alloc(512ull * 1024 * 2));
    unsigned short* ipw  = (unsigned short*)(ws + alloc(2ull * 2048 * 512 * 2));
    unsigned short* xpw  = (unsigned short*)(ws + alloc(2ull * 64 * 1024 * 2));
    unsigned short* opw  = (unsigned short*)(ws + alloc(2ull * 512 * 1024 * 2));
    unsigned short* xbf  = (unsigned short*)(ws + alloc(4096ull * 512 * 2));
    unsigned short* ubf  = (unsigned short*)(ws + alloc(8192ull * 512 * 2));
    // per-layer arena (stage-1 buffers aliased in)
    unsigned short* xzbf  = (unsigned short*)(ws + alloc(8192ull * 2048 * 2));
    unsigned short* xcbf  = (unsigned short*)(ws + alloc(8192ull * 1024 * 2));
    float*          xdbl  = (float*)(ws + alloc(8192ull * 64 * 4));
    float*          dtbuf = (float*)(ws + alloc(8192ull * 1024 * 4));
    unsigned short* ybf   = (unsigned short*)(ws + alloc(8192ull * 1024 * 2));
    float*          scan_ap = (float*)(ws + alloc((size_t)SCAN_NC * 8 * 16384 * 4));
    float*          scan_hf = (float*)(ws + alloc((size_t)SCAN_NC * 8 * 16384 * 4));
    unsigned short* dtpA  = (unsigned short*)(ws + alloc(8192ull * 128 * 2));
    unsigned short* dtpB  = (unsigned short*)(ws + alloc(1024ull * 128 * 2));
    float*          P      = (float*)xzbf;          // 32MB == 32MB, dead before in_proj
    unsigned short* catbf  = (unsigned short*)dtbuf; // 16MB <= 32MB, dead before dt GEMM
    float*          merged = (float*)xcbf;           // 16MB == 16MB, dead before conv

    // weight/activation conversions
    k_cvt<<<2048, 256, 0, stream>>>(x, xbf, 4096 * 512);
    k_cvt<<<512, 256, 0, stream>>>(merge_w, mw, 512 * 1024);
    k_cvt<<<2048, 256, 0, stream>>>(in_proj_w, ipw, 2 * 2048 * 512);
    k_cvt<<<128, 256, 0, stream>>>(x_proj_w, xpw, 2 * 64 * 1024);
    k_cvt<<<1024, 256, 0, stream>>>(out_proj_w, opw, 2 * 512 * 1024);
    k_upT<<<dim3(16, 16, 4), dim3(32, 32), 0, stream>>>(up_w, upT);

    // stage 1: transposed-conv as GEMM, assemble cat, merge GEMM, LN
    k_gemm<128, 0><<<dim3(16, 32), 256, 0, stream>>>(xbf, upT, P, nullptr, nullptr,
                                                     4096, 2048, 512);
    k_assemble<<<32768, 256, 0, stream>>>(P, skip, up_b, catbf);
    k_gemm<128, 0><<<dim3(4, 64), 256, 0, stream>>>(catbf, mw, merged, nullptr, merge_b,
                                                    8192, 512, 1024);
    k_ln<<<2048, 256, 0, stream>>>(merged, ln_w, ln_b, ubf);

    // two mamba layers
    for (int li = 0; li < 2; ++li) {
        k_gemm<128, 1><<<dim3(16, 64), 256, 0, stream>>>(ubf, ipw + (size_t)li * 2048 * 512,
                                                         nullptr, xzbf, nullptr, 8192, 2048, 512);
        k_conv<<<8192, 256, 0, stream>>>(xzbf, conv_w + li * 4096, conv_b + li * 1024, xcbf);
        k_gemm<64, 0><<<dim3(1, 64), 256, 0, stream>>>(xcbf, xpw + (size_t)li * 64 * 1024,
                                                       xdbl, nullptr, nullptr, 8192, 64, 1024);
        // dt path: exact split-bf16 GEMM (K=128) + fused hw-softplus epilogue
        k_dtpackA<<<1024, 256, 0, stream>>>(xdbl, dtpA);
        k_dtpackB<<<128, 256, 0, stream>>>(dt_proj_w + (size_t)li * 32768, dtpB);
        k_gemm<64, 2><<<dim3(16, 64), 256, 0, stream>>>(dtpA, dtpB, dtbuf, nullptr,
                                                        dt_proj_b + (size_t)li * 1024,
                                                        8192, 1024, 128);
        const float* Al = A_log + (size_t)li * 1024 * 16;
        const float* Dl = D_param + (size_t)li * 1024;
        k_scan_chunk<0><<<dim3(8, 8, SCAN_NC), 256, 0, stream>>>(
            dtbuf, xcbf, xdbl, xzbf, Al, Dl, scan_ap, scan_hf, ybf);
        k_scan_carry<<<512, 256, 0, stream>>>(scan_ap, scan_hf);
        k_scan_chunk<1><<<dim3(8, 8, SCAN_NC), 256, 0, stream>>>(
            dtbuf, xcbf, xdbl, xzbf, Al, Dl, scan_ap, scan_hf, ybf);
        if (li == 0)
            k_gemm<128, 1><<<dim3(4, 64), 256, 0, stream>>>(ybf, opw, nullptr, ubf, nullptr,
                                                            8192, 512, 1024);
        else
            k_gemm<128, 0><<<dim3(4, 64), 256, 0, stream>>>(ybf, opw + (size_t)512 * 1024,
                                                            out, nullptr, nullptr, 8192, 512, 1024);
    }
}

// Round 17
// 460.232 us; speedup vs baseline: 1.0611x; 1.0611x over previous
//
#include <hip/hip_runtime.h>

#define DEV __device__ __forceinline__

typedef short  bf16x8 __attribute__((ext_vector_type(8)));
typedef float  f32x4  __attribute__((ext_vector_type(4)));

DEV unsigned short f2b(float f) {
    unsigned int u = __float_as_uint(f);
    u += 0x7fffu + ((u >> 16) & 1u);
    return (unsigned short)(u >> 16);
}
DEV float b2f(unsigned short h) { return __uint_as_float((unsigned int)h << 16); }
DEV float silu(float x) { return x / (1.f + __expf(-x)); }
DEV float fexp2(float x) { return __builtin_amdgcn_exp2f(x); }   // raw v_exp_f32
DEV float flog2(float x) { return __builtin_amdgcn_logf(x); }    // raw v_log_f32

// async global->LDS, 16B per lane: HW writes lane l at ldsbase + l*16
typedef const __attribute__((address_space(1))) unsigned int GU32;
typedef __attribute__((address_space(3))) unsigned int LU32;
DEV void gload16(const unsigned short* g, unsigned short* l) {
    __builtin_amdgcn_global_load_lds((GU32*)g, (LU32*)l, 16, 0, 0);
}

// ---------------------------------------------------------------------------
// f32 -> bf16 elementwise convert (n multiple of 4)
__global__ __launch_bounds__(256) void k_cvt(const float* __restrict__ s,
                                             unsigned short* __restrict__ d, int n) {
    int i = (blockIdx.x * 256 + threadIdx.x) * 4;
    if (i + 3 < n) {
        float4 v = *(const float4*)(s + i);
        ushort4 o;
        o.x = f2b(v.x); o.y = f2b(v.y); o.z = f2b(v.z); o.w = f2b(v.w);
        *(ushort4*)(d + i) = o;
    }
}

// up_w (512 x 512 x 4) [i,o,k] -> upT[(k*512+o)*512 + i] bf16
__global__ void k_upT(const float* __restrict__ up_w, unsigned short* __restrict__ upT) {
    __shared__ float t[32][33];
    int tx = threadIdx.x, ty = threadIdx.y;
    int o0 = blockIdx.x * 32, i0 = blockIdx.y * 32, kz = blockIdx.z;
    t[ty][tx] = up_w[(size_t)(i0 + ty) * 2048 + (o0 + tx) * 4 + kz];
    __syncthreads();
    upT[(size_t)(kz * 512 + o0 + ty) * 512 + i0 + tx] = f2b(t[tx][ty]);
}

// dt packing: split-bf16 exact GEMM operands (K=32 -> K=128).
// A: dtraw = xdbl[:, 0:32] -> Ap[m][0:32]=xh, [32:64]=xl, [64:96]=xh, [96:128]=xl
__global__ __launch_bounds__(256) void k_dtpackA(const float* __restrict__ xdbl,
                                                 unsigned short* __restrict__ Ap) {
    int i = blockIdx.x * 256 + threadIdx.x;   // (m, r), r fastest
    int m = i >> 5, r = i & 31;
    float x = xdbl[(size_t)m * 64 + r];
    unsigned short xh = f2b(x);
    unsigned short xl = f2b(x - b2f(xh));
    size_t base = (size_t)m * 128;
    Ap[base + r]      = xh;
    Ap[base + 32 + r] = xl;
    Ap[base + 64 + r] = xh;
    Ap[base + 96 + r] = xl;
}

// B: dt_proj_w (1024 x 32) -> Bp[d][0:32]=wh, [32:64]=wl, [64:96]=wl, [96:128]=wh
// sum over K=128: xh*wh + xl*wl + xh*wl + xl*wh = (xh+xl)*(wh+wl)  (exact split)
__global__ __launch_bounds__(256) void k_dtpackB(const float* __restrict__ w,
                                                 unsigned short* __restrict__ Bp) {
    int i = blockIdx.x * 256 + threadIdx.x;   // (d, r)
    int d = i >> 5, r = i & 31;
    float x = w[(size_t)d * 32 + r];
    unsigned short wh = f2b(x);
    unsigned short wl = f2b(x - b2f(wh));
    size_t base = (size_t)d * 128;
    Bp[base + r]      = wh;
    Bp[base + 32 + r] = wl;
    Bp[base + 64 + r] = wl;
    Bp[base + 96 + r] = wh;
}

// ---------------------------------------------------------------------------
// bf16 MFMA GEMM, NT: C[m,n] = sum_k A[m,k]*B[n,k].  BK=32, 4 waves,
// m97-style global_load_lds staging (linear LDS, 16B/lane).
// XCD-aware block swizzle (T1): contiguous tile chunks per XCD for L2 reuse.
// Tiles: (BM,BN) in {(128,128),(128,64),(64,64)}.
// OUTMODE 0: f32 out, 1: bf16 out, 2: softplus -> f32 out (hw exp2/log2).
template <int BM, int BN, int OUTMODE>
__global__ __launch_bounds__(256) void k_gemm(const unsigned short* __restrict__ A,
                                              const unsigned short* __restrict__ B,
                                              float* __restrict__ Cf,
                                              unsigned short* __restrict__ Cb,
                                              const float* __restrict__ bias,
                                              int M, int N, int K) {
    constexpr int BK = 32;
    constexpr int WM = (BN == 128) ? 64 : 32;
    constexpr int WN = (BM == 64 && BN == 64) ? 32 : 64;
    constexpr int MI = WM / 16, NI = WN / 16;
    __shared__ unsigned short As[BM * BK];
    __shared__ unsigned short Bs[BN * BK];
    const int tid = threadIdx.x;
    const int wid = tid >> 6, lane = tid & 63;

    // XCD swizzle: hw bids round-robin XCDs; map same-XCD bids to contiguous tiles
    int bid = blockIdx.y * gridDim.x + blockIdx.x;
    const int nwg = gridDim.x * gridDim.y;
    if ((nwg & 7) == 0) {
        int cpx = nwg >> 3;
        bid = (bid & 7) * cpx + (bid >> 3);
    }
    const int bx = bid % gridDim.x, by = bid / gridDim.x;
    const int m0 = by * BM, n0 = bx * BN;

    int wr, wc;
    if (BN == 128)      { wr = wid >> 1; wc = wid & 1; }
    else if (BM == 128) { wr = wid;      wc = 0;       }
    else                { wr = wid & 1;  wc = wid >> 1; }
    const int wm0 = wr * WM, wn0 = wc * WN;
    const int fr = lane & 15, fh = lane >> 4;

    // staging geometry: wave w stages 16-row strips; lane l -> row w*16+(l>>2),
    // col (l&3)*8 ushorts; LDS dest is wave-uniform strip base (linear layout).
    const int srow = wid * 16 + (lane >> 2);
    const int scol = (lane & 3) * 8;
    const unsigned short* Ag = A + (size_t)(m0 + srow) * K + scol;
    const unsigned short* Bg = B + (size_t)(n0 + srow) * K + scol;
    unsigned short* AsB = &As[wid * 16 * BK];
    unsigned short* BsB = &Bs[wid * 16 * BK];

    f32x4 acc[MI][NI];
#pragma unroll
    for (int i = 0; i < MI; ++i)
#pragma unroll
        for (int j = 0; j < NI; ++j) acc[i][j] = (f32x4){0.f, 0.f, 0.f, 0.f};

    for (int k0 = 0; k0 < K; k0 += BK) {
        gload16(Ag + k0, AsB);
        if (BM == 128) gload16(Ag + (size_t)64 * K + k0, AsB + 64 * BK);
        gload16(Bg + k0, BsB);
        if (BN == 128) gload16(Bg + (size_t)64 * K + k0, BsB + 64 * BK);
        __syncthreads();
        bf16x8 av[MI], bv[NI];
#pragma unroll
        for (int mi = 0; mi < MI; ++mi)
            av[mi] = *(const bf16x8*)(&As[(wm0 + mi * 16 + fr) * BK + fh * 8]);
#pragma unroll
        for (int ni = 0; ni < NI; ++ni)
            bv[ni] = *(const bf16x8*)(&Bs[(wn0 + ni * 16 + fr) * BK + fh * 8]);
#pragma unroll
        for (int mi = 0; mi < MI; ++mi)
#pragma unroll
            for (int ni = 0; ni < NI; ++ni)
                acc[mi][ni] = __builtin_amdgcn_mfma_f32_16x16x32_bf16(av[mi], bv[ni],
                                                                      acc[mi][ni], 0, 0, 0);
        __syncthreads();
    }
    constexpr float LOG2E = 1.4426950408889634f;
    constexpr float LN2   = 0.6931471805599453f;
#pragma unroll
    for (int mi = 0; mi < MI; ++mi) {
#pragma unroll
        for (int ni = 0; ni < NI; ++ni) {
            int col = n0 + wn0 + ni * 16 + fr;
            float bb = bias ? bias[col] : 0.f;
#pragma unroll
            for (int j = 0; j < 4; ++j) {
                int row = m0 + wm0 + mi * 16 + fh * 4 + j;
                float v = acc[mi][ni][j] + bb;
                if (OUTMODE == 0)      Cf[(size_t)row * N + col] = v;
                else if (OUTMODE == 1) Cb[(size_t)row * N + col] = f2b(v);
                else                   Cf[(size_t)row * N + col] =
                    (v > 20.f) ? v : flog2(1.f + fexp2(v * LOG2E)) * LN2;
            }
        }
    }
}

// ---------------------------------------------------------------------------
// assemble cat row-major (8192 x 1024) bf16: [0,512)=xu from P, [512,1024)=skip
__global__ __launch_bounds__(256) void k_assemble(const float* __restrict__ P,
                                                  const float* __restrict__ skip,
                                                  const float* __restrict__ up_b,
                                                  unsigned short* __restrict__ catbf) {
    int bx = blockIdx.x;
    int m = bx >> 2;
    int c = (bx & 3) * 256 + threadIdx.x;
    int b = m >> 10, t = m & 1023, j = t >> 1;
    float v;
    if (c < 512) {
        size_t rb = (size_t)((b << 9) + j) * 2048;
        if (t & 1) {                       // odd t: k=2 @ j, k=0 @ j+1
            v = P[rb + 1024 + c];
            if (j + 1 < 512) v += P[rb + 2048 + c];
        } else {                           // even t: k=3 @ j-1, k=1 @ j
            v = P[rb + 512 + c];
            if (j >= 1) v += P[rb - 2048 + 1536 + c];
        }
        v += up_b[c];
    } else {
        v = skip[(size_t)m * 512 + (c - 512)];
    }
    catbf[(size_t)m * 1024 + c] = f2b(v);
}

// LayerNorm over 512, 4 rows per 256-block, writes bf16
__global__ __launch_bounds__(256) void k_ln(const float* __restrict__ merged,
                                            const float* __restrict__ w,
                                            const float* __restrict__ bvec,
                                            unsigned short* __restrict__ outb) {
    int row = blockIdx.x * 4 + (threadIdx.x >> 6);
    int lane = threadIdx.x & 63;
    const float* r = merged + (size_t)row * 512 + lane * 8;
    float4 v1 = *(const float4*)r;
    float4 v2 = *(const float4*)(r + 4);
    float xv[8] = {v1.x, v1.y, v1.z, v1.w, v2.x, v2.y, v2.z, v2.w};
    float s = 0.f, ss = 0.f;
#pragma unroll
    for (int e = 0; e < 8; ++e) { s += xv[e]; ss += xv[e] * xv[e]; }
#pragma unroll
    for (int m = 1; m < 64; m <<= 1) { s += __shfl_xor(s, m, 64); ss += __shfl_xor(ss, m, 64); }
    float mean = s * (1.f / 512.f);
    float var = ss * (1.f / 512.f) - mean * mean;
    float inv = rsqrtf(var + 1e-5f);
    unsigned short o8[8];
#pragma unroll
    for (int e = 0; e < 8; ++e) {
        int c = lane * 8 + e;
        o8[e] = f2b((xv[e] - mean) * inv * w[c] + bvec[c]);
    }
    *(int4*)(outb + (size_t)row * 512 + lane * 8) = *(const int4*)o8;
}

// causal depthwise conv K=4 + bias + silu; 4 channels/thread, bf16 in/out
__global__ __launch_bounds__(256) void k_conv(const unsigned short* __restrict__ xzb,
                                              const float* __restrict__ cw,
                                              const float* __restrict__ cb,
                                              unsigned short* __restrict__ xcb) {
    int i = blockIdx.x * 256 + threadIdx.x;   // 2.1M threads
    int m = i >> 8;
    int c0 = (i & 255) * 4;
    int l = m & 1023;
    float4 w0 = *(const float4*)(cw + (size_t)(c0 + 0) * 4);
    float4 w1 = *(const float4*)(cw + (size_t)(c0 + 1) * 4);
    float4 w2 = *(const float4*)(cw + (size_t)(c0 + 2) * 4);
    float4 w3 = *(const float4*)(cw + (size_t)(c0 + 3) * 4);
    float4 acc = *(const float4*)(cb + c0);
    const float* wp0 = (const float*)&w0;
    const float* wp1 = (const float*)&w1;
    const float* wp2 = (const float*)&w2;
    const float* wp3 = (const float*)&w3;
#pragma unroll
    for (int k = 0; k < 4; ++k) {
        int lp = l - 3 + k;
        if (lp >= 0) {
            ushort4 xv = *(const ushort4*)(xzb + (size_t)(m - l + lp) * 2048 + c0);
            acc.x = fmaf(wp0[k], b2f(xv.x), acc.x);
            acc.y = fmaf(wp1[k], b2f(xv.y), acc.y);
            acc.z = fmaf(wp2[k], b2f(xv.z), acc.z);
            acc.w = fmaf(wp3[k], b2f(xv.w), acc.w);
        }
    }
    ushort4 o = { f2b(silu(acc.x)), f2b(silu(acc.y)), f2b(silu(acc.z)), f2b(silu(acc.w)) };
    *(ushort4*)(xcb + (size_t)m * 1024 + c0) = o;
}

// ---------------------------------------------------------------------------
// Chunked selective scan.  L=1024 split into NC=32 chunks of CL=32.
// Thread = (b, d, chunk), 16 states in registers.  u input in bf16.
// PHASE 0: from h=0, store (exp2(A2*dtsum), h_final) per chunk -> ap, hf.
// PHASE 1: read h_init (in hf after carry), compute y, fused D*u + silu(z).
// Power fast path: A[s]=(s+1)*A[0] -> a_s = a1^(s+1) (guarded, exact fallback).
// Block = 256 threads = 256 consecutive d; grid (4 dgrp, 8 b, NC chunk).
constexpr int SCAN_NC = 32;
constexpr int SCAN_CL = 32;

template <int PHASE>
__global__ __launch_bounds__(256) void k_scan_chunk(
        const float* __restrict__ dt, const unsigned short* __restrict__ xcb,
        const float* __restrict__ xdbl, const unsigned short* __restrict__ xzb,
        const float* __restrict__ Alog, const float* __restrict__ Dp,
        float* __restrict__ ap, float* __restrict__ hf,
        unsigned short* __restrict__ ybf) {
    constexpr int CL = SCAN_CL;
    const int d = blockIdx.x * 256 + threadIdx.x;
    const int b = blockIdx.y, c = blockIdx.z;
    const size_t mbase = (size_t)b * 1024 + (size_t)c * CL;

    // stage this chunk's B/C slice of xdbl into LDS: [l][0..15]=B, [16..31]=C
    __shared__ float sBC[CL][32];
    {
        int row = threadIdx.x >> 3, q = threadIdx.x & 7;   // CL*8 == 256
        *(float4*)&sBC[row][q * 4] =
            *(const float4*)(xdbl + (mbase + row) * 64 + 32 + q * 4);
    }
    __syncthreads();

    constexpr float LOG2E = 1.4426950408889634f;
    float A2[16], h[16];
#pragma unroll
    for (int s = 0; s < 16; ++s) A2[s] = -expf(Alog[d * 16 + s]) * LOG2E;

    // integer-ratio check: A2[s] == (s+1)*A2[0] to ~1e-5 rel
    bool powok = true;
#pragma unroll
    for (int s = 1; s < 16; ++s)
        powok = powok && (fabsf(A2[s] - (float)(s + 1) * A2[0]) <=
                          1e-5f * fabsf(A2[s]));

    const size_t sumbase = ((size_t)(b * SCAN_NC + c) << 14) + d * 16;
    if (PHASE == 0) {
#pragma unroll
        for (int s = 0; s < 16; ++s) h[s] = 0.f;
    } else {
#pragma unroll
        for (int s = 0; s < 16; s += 4)
            *(f32x4*)&h[s] = *(const f32x4*)(hf + sumbase + s);
    }
    float dtsum = 0.f;
    const float Dv = (PHASE == 1) ? Dp[d] : 0.f;

    // software-pipelined dt/u loads: issue next-l loads before current compute
    const size_t mrow = mbase * 1024 + d;
    float dtv = dt[mrow];
    float uv  = b2f(xcb[mrow]);
#pragma unroll 2
    for (int l = 0; l < CL; ++l) {
        const size_t m = mbase + l;
        const float dtv_c = dtv, uv_c = uv;
        if (l + 1 < CL) {
            dtv = dt[mrow + (size_t)(l + 1) * 1024];
            uv  = b2f(xcb[mrow + (size_t)(l + 1) * 1024]);
        }
        float zv;
        if (PHASE == 1) zv = b2f(xzb[m * 2048 + 1024 + d]);
        const float dtu = dtv_c * uv_c;
        if (PHASE == 0) dtsum += dtv_c;
        float Bv[16], Cv[16];
#pragma unroll
        for (int q = 0; q < 4; ++q) {
            *(float4*)&Bv[q * 4] = *(const float4*)&sBC[l][q * 4];
            if (PHASE == 1)
                *(float4*)&Cv[q * 4] = *(const float4*)&sBC[l][16 + q * 4];
        }
        float p = 0.f;
        if (powok) {
            const float a1 = fexp2(dtv_c * A2[0]);
            float a = a1;
#pragma unroll
            for (int s = 0; s < 16; ++s) {
                h[s] = fmaf(a, h[s], dtu * Bv[s]);
                if (PHASE == 1) p = fmaf(h[s], Cv[s], p);
                a *= a1;
            }
        } else {
#pragma unroll
            for (int s = 0; s < 16; ++s) {
                float a = fexp2(dtv_c * A2[s]);
                h[s] = fmaf(a, h[s], dtu * Bv[s]);
                if (PHASE == 1) p = fmaf(h[s], Cv[s], p);
            }
        }
        if (PHASE == 1) {
            ybf[m * 1024 + d] = f2b((p + Dv * uv_c) * silu(zv));
        }
    }
    if (PHASE == 0) {
        float aprod[16];
        if (powok) {
            const float ap1 = fexp2(A2[0] * dtsum);
            float a = ap1;
#pragma unroll
            for (int s = 0; s < 16; ++s) { aprod[s] = a; a *= ap1; }
        } else {
#pragma unroll
            for (int s = 0; s < 16; ++s) aprod[s] = fexp2(A2[s] * dtsum);
        }
#pragma unroll
        for (int s = 0; s < 16; s += 4) {
            *(f32x4*)(ap + sumbase + s) = *(const f32x4*)&aprod[s];
            *(f32x4*)(hf + sumbase + s) = *(const f32x4*)&h[s];
        }
    }
}

// carry scan over chunk summaries; rewrites hf[c] with h_init for chunk c.
__global__ __launch_bounds__(256) void k_scan_carry(const float* __restrict__ ap,
                                                    float* __restrict__ hf) {
    int i = blockIdx.x * 256 + threadIdx.x;   // (b, d*16+s)
    int b = i >> 14, ds = i & 16383;
    float h = 0.f;
    for (int c = 0; c < SCAN_NC; ++c) {
        size_t idx = ((size_t)(b * SCAN_NC + c) << 14) + ds;
        float a = ap[idx], f = hf[idx];
        hf[idx] = h;
        h = fmaf(a, h, f);
    }
}

// ---------------------------------------------------------------------------
extern "C" void kernel_launch(void* const* d_in, const int* in_sizes, int n_in,
                              void* d_out, int out_size, void* d_ws, size_t ws_size,
                              hipStream_t stream) {
    const float* x         = (const float*)d_in[0];
    const float* skip      = (const float*)d_in[1];
    const float* up_w      = (const float*)d_in[2];
    const float* up_b      = (const float*)d_in[3];
    const float* merge_w   = (const float*)d_in[4];
    const float* merge_b   = (const float*)d_in[5];
    const float* ln_w      = (const float*)d_in[6];
    const float* ln_b      = (const float*)d_in[7];
    const float* in_proj_w = (const float*)d_in[8];
    const float* conv_w    = (const float*)d_in[9];
    const float* conv_b    = (const float*)d_in[10];
    const float* x_proj_w  = (const float*)d_in[11];
    const float* dt_proj_w = (const float*)d_in[12];
    const float* dt_proj_b = (const float*)d_in[13];
    const float* A_log     = (const float*)d_in[14];
    const float* D_param   = (const float*)d_in[15];
    const float* out_proj_w= (const float*)d_in[16];
    float* out = (float*)d_out;

    char* ws = (char*)d_ws;
    size_t off = 0;
    auto alloc = [&](size_t bytes) { size_t r = off; off += (bytes + 255) & ~(size_t)255; return r; };

    // persistent
    unsigned short* upT  = (unsigned short*)(ws + alloc(2048ull * 512 * 2));
    unsigned short* mw   = (unsigned short*)(ws + alloc(512ull * 1024 * 2));
    unsigned short* ipw  = (unsigned short*)(ws + alloc(2ull * 2048 * 512 * 2));
    unsigned short* xpw  = (unsigned short*)(ws + alloc(2ull * 64 * 1024 * 2));
    unsigned short* opw  = (unsigned short*)(ws + alloc(2ull * 512 * 1024 * 2));
    unsigned short* xbf  = (unsigned short*)(ws + alloc(4096ull * 512 * 2));
    unsigned short* ubf  = (unsigned short*)(ws + alloc(8192ull * 512 * 2));
    // per-layer arena (stage-1 buffers aliased in)
    unsigned short* xzbf  = (unsigned short*)(ws + alloc(8192ull * 2048 * 2));
    unsigned short* xcbf  = (unsigned short*)(ws + alloc(8192ull * 1024 * 2));
    float*          xdbl  = (float*)(ws + alloc(8192ull * 64 * 4));
    float*          dtbuf = (float*)(ws + alloc(8192ull * 1024 * 4));
    unsigned short* ybf   = (unsigned short*)(ws + alloc(8192ull * 1024 * 2));
    float*          scan_ap = (float*)(ws + alloc((size_t)SCAN_NC * 8 * 16384 * 4));
    float*          scan_hf = (float*)(ws + alloc((size_t)SCAN_NC * 8 * 16384 * 4));
    unsigned short* dtpA  = (unsigned short*)(ws + alloc(8192ull * 128 * 2));
    unsigned short* dtpB  = (unsigned short*)(ws + alloc(1024ull * 128 * 2));
    float*          P      = (float*)xzbf;          // 32MB == 32MB, dead before in_proj
    unsigned short* catbf  = (unsigned short*)dtbuf; // 16MB <= 32MB, dead before dt GEMM
    float*          merged = (float*)xcbf;           // 16MB == 16MB, dead before conv

    // weight/activation conversions
    k_cvt<<<2048, 256, 0, stream>>>(x, xbf, 4096 * 512);
    k_cvt<<<512, 256, 0, stream>>>(merge_w, mw, 512 * 1024);
    k_cvt<<<2048, 256, 0, stream>>>(in_proj_w, ipw, 2 * 2048 * 512);
    k_cvt<<<128, 256, 0, stream>>>(x_proj_w, xpw, 2 * 64 * 1024);
    k_cvt<<<1024, 256, 0, stream>>>(out_proj_w, opw, 2 * 512 * 1024);
    k_upT<<<dim3(16, 16, 4), dim3(32, 32), 0, stream>>>(up_w, upT);

    // stage 1: transposed-conv as GEMM, assemble cat, merge GEMM, LN
    k_gemm<128, 128, 0><<<dim3(16, 32), 256, 0, stream>>>(xbf, upT, P, nullptr, nullptr,
                                                          4096, 2048, 512);
    k_assemble<<<32768, 256, 0, stream>>>(P, skip, up_b, catbf);
    k_gemm<128, 128, 0><<<dim3(4, 64), 256, 0, stream>>>(catbf, mw, merged, nullptr, merge_b,
                                                         8192, 512, 1024);
    k_ln<<<2048, 256, 0, stream>>>(merged, ln_w, ln_b, ubf);

    // two mamba layers
    for (int li = 0; li < 2; ++li) {
        k_gemm<128, 128, 1><<<dim3(16, 64), 256, 0, stream>>>(ubf, ipw + (size_t)li * 2048 * 512,
                                                              nullptr, xzbf, nullptr, 8192, 2048, 512);
        k_conv<<<8192, 256, 0, stream>>>(xzbf, conv_w + li * 4096, conv_b + li * 1024, xcbf);
        k_gemm<64, 64, 0><<<dim3(1, 128), 256, 0, stream>>>(xcbf, xpw + (size_t)li * 64 * 1024,
                                                            xdbl, nullptr, nullptr, 8192, 64, 1024);
        // dt path: exact split-bf16 GEMM (K=128) + fused hw-softplus epilogue
        k_dtpackA<<<1024, 256, 0, stream>>>(xdbl, dtpA);
        k_dtpackB<<<128, 256, 0, stream>>>(dt_proj_w + (size_t)li * 32768, dtpB);
        k_gemm<128, 64, 2><<<dim3(16, 64), 256, 0, stream>>>(dtpA, dtpB, dtbuf, nullptr,
                                                             dt_proj_b + (size_t)li * 1024,
                                                             8192, 1024, 128);
        const float* Al = A_log + (size_t)li * 1024 * 16;
        const float* Dl = D_param + (size_t)li * 1024;
        k_scan_chunk<0><<<dim3(4, 8, SCAN_NC), 256, 0, stream>>>(
            dtbuf, xcbf, xdbl, xzbf, Al, Dl, scan_ap, scan_hf, ybf);
        k_scan_carry<<<512, 256, 0, stream>>>(scan_ap, scan_hf);
        k_scan_chunk<1><<<dim3(4, 8, SCAN_NC), 256, 0, stream>>>(
            dtbuf, xcbf, xdbl, xzbf, Al, Dl, scan_ap, scan_hf, ybf);
        if (li == 0)
            k_gemm<128, 128, 1><<<dim3(4, 64), 256, 0, stream>>>(ybf, opw, nullptr, ubf, nullptr,
                                                                 8192, 512, 1024);
        else
            k_gemm<128, 128, 0><<<dim3(4, 64), 256, 0, stream>>>(ybf, opw + (size_t)512 * 1024,
                                                                 out, nullptr, nullptr, 8192, 512, 1024);
    }
}